// Round 9
// baseline (178.911 us; speedup 1.0000x reference)
//
#include <hip/hip_runtime.h>

// DeformConv fused fp16, A-fragments-in-registers edition.
// Gather lanes == MFMA-A lanes -> corner combine lands directly in af VGPRs;
// val LDS round-trip eliminated; B staged full-width once per tap; 2 barriers/tap.
// B=4, C=128, H=W=96, O=128, 3x3 s1 p1 d1, G=1.
#define CIN   128
#define HH    96
#define WW    96
#define OUTC  128
#define HWSZ  9216
#define KK    9
#define KTOT  1152        // k' = tap*128 + c (tap-major)

typedef _Float16 f16x8 __attribute__((ext_vector_type(8)));
typedef _Float16 h2    __attribute__((ext_vector_type(2)));
typedef float    f32x4 __attribute__((ext_vector_type(4)));

__device__ __forceinline__ unsigned short f2h(float f) {
  _Float16 h = (_Float16)f;                      // v_cvt_f16_f32 (RNE)
  return __builtin_bit_cast(unsigned short, h);
}
// pack two floats to f16x2 (RTZ) : 1 VALU
__device__ __forceinline__ unsigned pack_h(float v0, float v1) {
  auto r = __builtin_amdgcn_cvt_pkrtz(v0, v1);   // lo = v0, hi = v1
  return __builtin_bit_cast(unsigned, r);
}

// ws layout (u16 offsets):
//   wtb   f16[128][1152] @ 0         (k' = tap*128+c)
//   wt2b  f16[32][1152]  @ 147456    (oc 0-17 offset, 18-26 mask, 27-31 zero)
//   bias32 f32[32]       @ 184320
//   xn    f16[4][9216][128] @ 184384 (NHWC)
//   x2n   f16[4][9216][128] @ 184384+4718592
#define WT2B_O 147456
#define BIAS_O 184320
#define XN_O   184384
#define X2N_O  (184384 + 4718592)

// Combined prep: blocks [0,1152) = NCHW->NHWC f16 transpose of x/x2
// (float4 loads: 4 px/lane, 16 c-rows/pass; uint4 stores);
// blocks [1152,1873) = weight reorder/cast.
__global__ __launch_bounds__(256) void prep_all(
    const float* __restrict__ x, const float* __restrict__ x2,
    const float* __restrict__ offw, const float* __restrict__ maskw,
    const float* __restrict__ defw, const float* __restrict__ offb,
    const float* __restrict__ maskb, void* __restrict__ wsv) {
  int bid = blockIdx.x;
  int t = threadIdx.x;
  if (bid < 1152) {
    // u16 tile[64 px][136] (word stride 68): word (c>>1) holds {c, c+1}
    __shared__ unsigned short tile[64][136];
    int tsel = bid / 576;
    int rem = bid - tsel * 576;
    int b = rem / 144;
    int hw0 = (rem % 144) * 64;
    const float* src = tsel ? x2 : x;
    unsigned short* dst = (unsigned short*)wsv + (tsel ? X2N_O : XN_O);
    unsigned* tw = (unsigned*)&tile[0][0];
    int c2  = t & 15;        // channel-pair index within pass
    int px4 = t >> 4;        // 0..15 -> px = px4*4..+3
#pragma unroll
    for (int pass = 0; pass < 4; ++pass) {
      int c = pass * 32 + c2 * 2;
      const float* r0 = src + ((size_t)(b * CIN + c)) * HWSZ + hw0 + px4 * 4;
      float4 f0 = *(const float4*)r0;          // 4 px of channel c
      float4 f1 = *(const float4*)(r0 + HWSZ); // 4 px of channel c+1
      int wb = pass * 16 + c2;                 // = c>>1
      tw[(px4 * 4 + 0) * 68 + wb] = pack_h(f0.x, f1.x);
      tw[(px4 * 4 + 1) * 68 + wb] = pack_h(f0.y, f1.y);
      tw[(px4 * 4 + 2) * 68 + wb] = pack_h(f0.z, f1.z);
      tw[(px4 * 4 + 3) * 68 + wb] = pack_h(f0.w, f1.w);
    }
    __syncthreads();
    unsigned* drow = (unsigned*)(dst + ((size_t)(b * HWSZ + hw0)) * 128);
    int w4 = t & 15, pxr = t >> 4;
#pragma unroll
    for (int pass = 0; pass < 4; ++pass) {
      int px = pass * 16 + pxr;
      uint4 v = *(const uint4*)&tw[px * 68 + w4 * 4];
      *(uint4*)&drow[(size_t)px * 64 + w4 * 4] = v;
    }
    return;
  }
  unsigned short* wtb  = (unsigned short*)wsv;
  unsigned short* wt2b = wtb + WT2B_O;
  float* bias32 = (float*)(wtb + BIAS_O);
  int idx = (bid - 1152) * 256 + t;
  if (idx < OUTC * KTOT) {
    int o = idx / KTOT, r = idx - o * KTOT;
    int c = r / KK, tap = r - c * KK;
    wtb[o * KTOT + tap * 128 + c] = f2h(defw[idx]);
  } else if (idx < OUTC * KTOT + 32 * KTOT) {
    int j = idx - OUTC * KTOT;
    int oc = j / KTOT, r = j - oc * KTOT;
    int c = r / KK, tap = r - c * KK;
    float v = 0.f;
    if (oc < 18)      v = offw[j];
    else if (oc < 27) v = maskw[j - 18 * KTOT];
    wt2b[oc * KTOT + tap * 128 + c] = f2h(v);
  } else if (idx < OUTC * KTOT + 32 * KTOT + 32) {
    int j = idx - OUTC * KTOT - 32 * KTOT;
    float v = 0.f;
    if (j < 18) v = offb[j]; else if (j < 27) v = maskb[j - 18];
    bias32[j] = v;
  }
}

// Fused: block = 64-px strip; wave w = m-tile w (16 px) x all 128 oc (M-split).
// Lane roles EVERYWHERE: l15 = px-in-m-tile (MFMA A row), quad = channel octet.
// Per corner cr: 4 loads (ks) at pos*256B + ks*64 + quad*16 -> combine with
// v_pk_fma_f16 directly into af[ks]. No val tile, no A LDS traffic.
// B staged once per tap: 128 oc rows x 64 dw, stride 68 (2-way-free reads).
__global__ __launch_bounds__(256, 3) void fused(
    const float* __restrict__ defb, const void* __restrict__ wsv,
    float* __restrict__ out) {
  const unsigned short* wtb  = (const unsigned short*)wsv;
  const unsigned short* wt2b = wtb + WT2B_O;
  const float* bias32 = (const float*)(wtb + BIAS_O);
  const unsigned short* xn  = wtb + XN_O;
  const unsigned short* x2n = wtb + X2N_O;

  __shared__ unsigned bw[128 * 68];        // 34.8 KB: B full tap-tile
  __shared__ float om[32][68];             // 8.7 KB
  __shared__ unsigned sidxw[KK * 4 * 64];  // 9.2 KB: [(tap*4+cr)*64+px] idx|w<<16

  int t = threadIdx.x;
  int w = t >> 6;
  int l15 = t & 15, quad = (t >> 4) & 3;
  int rb = blockIdx.x;
  int bid = (rb & 7) * 72 + (rb >> 3);     // XCD swizzle
  int b = bid / 144;
  int pblk = (bid % 144) * 64;

  // this lane's A-row pixel
  int prow = pblk + w * 16 + l15;
  int ph = prow / WW;
  int pw_ = prow - ph * WW;

  // ===== phase 1: offset/mask GEMM =====
  f32x4 oa0 = {0.f, 0.f, 0.f, 0.f};
  f32x4 oa1 = {0.f, 0.f, 0.f, 0.f};
  const unsigned short* x2nb = x2n + ((size_t)b * HWSZ) * 128;
  for (int tap = 0; tap < KK; ++tap) {
    int ky = tap / 3 - 1, kx = tap % 3 - 1;
    int y = ph + ky, xx = pw_ + kx;
    bool ok = ((unsigned)y < HH) && ((unsigned)xx < WW);
    int pos = ok ? (y * WW + xx) : 0;
    const unsigned short* p = x2nb + ((size_t)pos << 7) + quad * 8;
    uint4 u[4];
#pragma unroll
    for (int ks = 0; ks < 4; ++ks) u[ks] = *(const uint4*)(p + ks * 32);
#pragma unroll
    for (int j = 0; j < 2; ++j) {          // stage 32 oc rows x 64 dw
      int cc = t + 256 * j;
      int row = cc >> 4, c16 = cc & 15;
      *(uint4*)&bw[row * 68 + c16 * 4] =
          *(const uint4*)(wt2b + (size_t)row * KTOT + tap * 128 + c16 * 8);
    }
    __syncthreads();
#pragma unroll
    for (int ks = 0; ks < 4; ++ks) {
      uint4 m = u[ks];
      if (!ok) m = make_uint4(0u, 0u, 0u, 0u);
      f16x8 af = __builtin_bit_cast(f16x8, m);
      f16x8 b0 = *(const f16x8*)&bw[(size_t)l15 * 68 + ks * 16 + quad * 4];
      f16x8 b1 = *(const f16x8*)&bw[(size_t)(l15 + 16) * 68 + ks * 16 + quad * 4];
      oa0 = __builtin_amdgcn_mfma_f32_16x16x32_f16(af, b0, oa0, 0, 0, 0);
      oa1 = __builtin_amdgcn_mfma_f32_16x16x32_f16(af, b1, oa1, 0, 0, 0);
    }
    __syncthreads();
  }
  // dump om (+bias): C layout col=l15 (oc), row=quad*4+reg (px in m-tile)
#pragma unroll
  for (int nt = 0; nt < 2; ++nt) {
    f32x4 a = nt ? oa1 : oa0;
    int oc = nt * 16 + l15;
    float bia = bias32[oc];
#pragma unroll
    for (int r = 0; r < 4; ++r)
      om[oc][w * 16 + quad * 4 + r] = a[r] + bia;
  }
  __syncthreads();

  // ===== phase 2: bilinear params -> sidxw =====
  for (int e = t; e < KK * 64; e += 256) {
    int tap = e >> 6, pp = e & 63;
    int gp2 = pblk + pp;
    int h = gp2 / WW, ww_ = gp2 % WW;
    float dy = om[2 * tap][pp], dx = om[2 * tap + 1][pp];
    float mr = om[18 + tap][pp];
    float m = 1.f / (1.f + __expf(-mr));
    float py  = (float)(h + tap / 3 - 1) + dy;
    float pxx = (float)(ww_ + tap % 3 - 1) + dx;
    float y0f = floorf(py), x0f = floorf(pxx);
    int y0 = (int)y0f, x0 = (int)x0f;
    float ly = py - y0f, lx = pxx - x0f;
    int y1 = y0 + 1, x1 = x0 + 1;
    bool vy0 = (unsigned)y0 < HH, vy1 = (unsigned)y1 < HH;
    bool vx0 = (unsigned)x0 < WW, vx1 = (unsigned)x1 < WW;
    int cy0 = min(max(y0, 0), HH - 1), cy1 = min(max(y1, 0), HH - 1);
    int cx0 = min(max(x0, 0), WW - 1), cx1 = min(max(x1, 0), WW - 1);
    unsigned i00 = cy0 * WW + cx0, i01 = cy0 * WW + cx1;
    unsigned i10 = cy1 * WW + cx0, i11 = cy1 * WW + cx1;
    float w00 = (vy0 && vx0) ? m * (1.f - ly) * (1.f - lx) : 0.f;
    float w01 = (vy0 && vx1) ? m * (1.f - ly) * lx         : 0.f;
    float w10 = (vy1 && vx0) ? m * ly * (1.f - lx)         : 0.f;
    float w11 = (vy1 && vx1) ? m * ly * lx                 : 0.f;
    sidxw[(tap * 4 + 0) * 64 + pp] = i00 | ((unsigned)f2h(w00) << 16);
    sidxw[(tap * 4 + 1) * 64 + pp] = i01 | ((unsigned)f2h(w01) << 16);
    sidxw[(tap * 4 + 2) * 64 + pp] = i10 | ((unsigned)f2h(w10) << 16);
    sidxw[(tap * 4 + 3) * 64 + pp] = i11 | ((unsigned)f2h(w11) << 16);
  }
  __syncthreads();

  // ===== phase 3: deformable GEMM (A in registers) =====
  f32x4 acc[8];
#pragma unroll
  for (int nt = 0; nt < 8; ++nt) acc[nt] = (f32x4){0.f, 0.f, 0.f, 0.f};
  const unsigned short* xnb = xn + ((size_t)b * HWSZ) * 128;

  for (int tap = 0; tap < KK; ++tap) {
    // per-corner idx|weight for this lane's pixel
    unsigned sw[4];
#pragma unroll
    for (int cr = 0; cr < 4; ++cr)
      sw[cr] = sidxw[(tap * 4 + cr) * 64 + w * 16 + l15];
    // gather: v[cr][ks] = 16B of corner cr, channels ks*32+quad*8..+8
    uint4 v[4][4];
#pragma unroll
    for (int cr = 0; cr < 4; ++cr) {
      const unsigned short* p =
          xnb + ((size_t)(sw[cr] & 0xffffu) << 7) + quad * 8;
#pragma unroll
      for (int ks = 0; ks < 4; ++ks)
        v[cr][ks] = *(const uint4*)(p + ks * 32);
    }
    // stage B full tile (128 oc rows x 64 dw)
#pragma unroll
    for (int j = 0; j < 8; ++j) {
      int cc = t + 256 * j;
      int row = cc >> 4, c16 = cc & 15;
      *(uint4*)&bw[row * 68 + c16 * 4] =
          *(const uint4*)(wtb + (size_t)row * KTOT + tap * 128 + c16 * 8);
    }
    // combine corners -> af (packed f16 FMA, straight into A fragments)
    f16x8 af[4];
#pragma unroll
    for (int ks = 0; ks < 4; ++ks) {
      h2 f[4];
#pragma unroll
      for (int j = 0; j < 4; ++j) f[j] = (h2){(_Float16)0.f, (_Float16)0.f};
#pragma unroll
      for (int cr = 0; cr < 4; ++cr) {
        _Float16 wh =
            __builtin_bit_cast(_Float16, (unsigned short)(sw[cr] >> 16));
        h2 wpk = {wh, wh};
        const h2* a = (const h2*)&v[cr][ks];
#pragma unroll
        for (int j = 0; j < 4; ++j)
          f[j] += wpk * a[j];                    // v_pk_fma_f16
      }
      uint4 u = make_uint4(__builtin_bit_cast(unsigned, f[0]),
                           __builtin_bit_cast(unsigned, f[1]),
                           __builtin_bit_cast(unsigned, f[2]),
                           __builtin_bit_cast(unsigned, f[3]));
      af[ks] = __builtin_bit_cast(f16x8, u);
    }
    __syncthreads();
#pragma unroll
    for (int ks = 0; ks < 4; ++ks)
#pragma unroll
      for (int nt = 0; nt < 8; ++nt) {
        f16x8 bb = *(const f16x8*)&bw[(size_t)(nt * 16 + l15) * 68 +
                                      ks * 16 + quad * 4];
        acc[nt] =
            __builtin_amdgcn_mfma_f32_16x16x32_f16(af[ks], bb, acc[nt], 0, 0, 0);
      }
    __syncthreads();
  }

  // ===== phase 4: epilogue =====
  for (int r = 0; r < 4; ++r) {
    f32x4 a0 = acc[2 * r], a1 = acc[2 * r + 1];
    float db0 = defb[r * 32 + l15];
    float db1 = defb[r * 32 + 16 + l15];
    if (r) __syncthreads();
#pragma unroll
    for (int reg = 0; reg < 4; ++reg) {
      om[l15]     [w * 16 + quad * 4 + reg] = a0[reg] + db0;
      om[16 + l15][w * 16 + quad * 4 + reg] = a1[reg] + db1;
    }
    __syncthreads();
    int row = t >> 4;
    int col4 = (t & 15) * 4;
#pragma unroll
    for (int hrow = 0; hrow < 2; ++hrow) {
      int rr = row + hrow * 16;
      float4 vv = *(float4*)&om[rr][col4];
      *(float4*)&out[((size_t)b * OUTC + r * 32 + rr) * HWSZ + pblk + col4] = vv;
    }
  }
}

extern "C" void kernel_launch(void* const* d_in, const int* in_sizes, int n_in,
                              void* d_out, int out_size, void* d_ws, size_t ws_size,
                              hipStream_t stream) {
  const float* x     = (const float*)d_in[0];
  const float* x2    = (const float*)d_in[1];
  const float* offw  = (const float*)d_in[2];
  const float* offb  = (const float*)d_in[3];
  const float* maskw = (const float*)d_in[4];
  const float* maskb = (const float*)d_in[5];
  const float* defw  = (const float*)d_in[6];
  const float* defb  = (const float*)d_in[7];
  float* out = (float*)d_out;

  hipLaunchKernelGGL(prep_all, dim3(1873), dim3(256), 0, stream,
                     x, x2, offw, maskw, defw, offb, maskb, d_ws);
  hipLaunchKernelGGL(fused, dim3(576), dim3(256), 0, stream, defb, d_ws, out);
}

// Round 10
// 142.240 us; speedup vs baseline: 1.2578x; 1.2578x over previous
//
#include <hip/hip_runtime.h>

// DeformConv fused fp16, 2x2 wave-grid + direct epilogue + om-in-val alias.
// B=4, C=128, H=W=96, O=128, 3x3 s1 p1 d1, G=1.
#define CIN   128
#define HH    96
#define WW    96
#define OUTC  128
#define HWSZ  9216
#define KK    9
#define KTOT  1152        // k' = tap*128 + c (tap-major)

typedef _Float16 f16x8 __attribute__((ext_vector_type(8)));
typedef _Float16 h2    __attribute__((ext_vector_type(2)));
typedef float    f32x4 __attribute__((ext_vector_type(4)));

__device__ __forceinline__ unsigned short f2h(float f) {
  _Float16 h = (_Float16)f;                      // v_cvt_f16_f32 (RNE)
  return __builtin_bit_cast(unsigned short, h);
}
// pack two floats to f16x2 (RTZ) : 1 VALU
__device__ __forceinline__ unsigned pack_h(float v0, float v1) {
  auto r = __builtin_amdgcn_cvt_pkrtz(v0, v1);   // lo = v0, hi = v1
  return __builtin_bit_cast(unsigned, r);
}

// ws layout (u16 offsets):
//   wtb   f16[128][1152] @ 0         (k' = tap*128+c)
//   wt2b  f16[32][1152]  @ 147456    (oc 0-17 offset, 18-26 mask, 27-31 zero)
//   bias32 f32[32]       @ 184320
//   xn    f16[4][9216][128] @ 184384 (NHWC)
//   x2n   f16[4][9216][128] @ 184384+4718592
#define WT2B_O 147456
#define BIAS_O 184320
#define XN_O   184384
#define X2N_O  (184384 + 4718592)

// Combined prep: blocks [0,1152) = NCHW->NHWC f16 transpose of x/x2
// (float4 loads: 4 px/lane, 16 c-rows/pass; uint4 stores);
// blocks [1152,1873) = weight reorder/cast.
__global__ __launch_bounds__(256) void prep_all(
    const float* __restrict__ x, const float* __restrict__ x2,
    const float* __restrict__ offw, const float* __restrict__ maskw,
    const float* __restrict__ defw, const float* __restrict__ offb,
    const float* __restrict__ maskb, void* __restrict__ wsv) {
  int bid = blockIdx.x;
  int t = threadIdx.x;
  if (bid < 1152) {
    // u16 tile[64 px][136] (word stride 68): word (c>>1) holds {c, c+1}
    __shared__ unsigned short tile[64][136];
    int tsel = bid / 576;
    int rem = bid - tsel * 576;
    int b = rem / 144;
    int hw0 = (rem % 144) * 64;
    const float* src = tsel ? x2 : x;
    unsigned short* dst = (unsigned short*)wsv + (tsel ? X2N_O : XN_O);
    unsigned* tw = (unsigned*)&tile[0][0];
    int c2  = t & 15;        // channel-pair index within pass
    int px4 = t >> 4;        // 0..15 -> px = px4*4..+3
#pragma unroll
    for (int pass = 0; pass < 4; ++pass) {
      int c = pass * 32 + c2 * 2;
      const float* r0 = src + ((size_t)(b * CIN + c)) * HWSZ + hw0 + px4 * 4;
      float4 f0 = *(const float4*)r0;          // 4 px of channel c
      float4 f1 = *(const float4*)(r0 + HWSZ); // 4 px of channel c+1
      int wb = pass * 16 + c2;                 // = c>>1
      tw[(px4 * 4 + 0) * 68 + wb] = pack_h(f0.x, f1.x);
      tw[(px4 * 4 + 1) * 68 + wb] = pack_h(f0.y, f1.y);
      tw[(px4 * 4 + 2) * 68 + wb] = pack_h(f0.z, f1.z);
      tw[(px4 * 4 + 3) * 68 + wb] = pack_h(f0.w, f1.w);
    }
    __syncthreads();
    unsigned* drow = (unsigned*)(dst + ((size_t)(b * HWSZ + hw0)) * 128);
    int w4 = t & 15, pxr = t >> 4;
#pragma unroll
    for (int pass = 0; pass < 4; ++pass) {
      int px = pass * 16 + pxr;
      uint4 v = *(const uint4*)&tw[px * 68 + w4 * 4];
      *(uint4*)&drow[(size_t)px * 64 + w4 * 4] = v;
    }
    return;
  }
  unsigned short* wtb  = (unsigned short*)wsv;
  unsigned short* wt2b = wtb + WT2B_O;
  float* bias32 = (float*)(wtb + BIAS_O);
  int idx = (bid - 1152) * 256 + t;
  if (idx < OUTC * KTOT) {
    int o = idx / KTOT, r = idx - o * KTOT;
    int c = r / KK, tap = r - c * KK;
    wtb[o * KTOT + tap * 128 + c] = f2h(defw[idx]);
  } else if (idx < OUTC * KTOT + 32 * KTOT) {
    int j = idx - OUTC * KTOT;
    int oc = j / KTOT, r = j - oc * KTOT;
    int c = r / KK, tap = r - c * KK;
    float v = 0.f;
    if (oc < 18)      v = offw[j];
    else if (oc < 27) v = maskw[j - 18 * KTOT];
    wt2b[oc * KTOT + tap * 128 + c] = f2h(v);
  } else if (idx < OUTC * KTOT + 32 * KTOT + 32) {
    int j = idx - OUTC * KTOT - 32 * KTOT;
    float v = 0.f;
    if (j < 18) v = offb[j]; else if (j < 27) v = maskb[j - 18];
    bias32[j] = v;
  }
}

// Fused: block = 64-px strip.
// Gather roles: wave w gathers px strip w*16..+15, lanes (quad = px-in-group,
// l15 = channel octet) -> full 256B row reads (4 segments/instr),
// corners combined in-lane with v_pk_fma_f16, written to val.
// Phase-3 MFMA: 2x2 wave grid (mw=w&1, nw=w>>1): wave computes
// px mw*32..+31 x oc {nw*32..+31, 64+nw*32..+31} (2x B-read redundancy).
// om (offset/mask results) ALIASES val storage: om live only phase1end->
// phase2end, when val's A-tile is dead. Epilogue: direct f32x4 stores from
// acc (reg = 4 consecutive px) -- no LDS, no barriers.
__global__ __launch_bounds__(256, 3) void fused(
    const float* __restrict__ defb, const void* __restrict__ wsv,
    float* __restrict__ out) {
  const unsigned short* wtb  = (const unsigned short*)wsv;
  const unsigned short* wt2b = wtb + WT2B_O;
  const float* bias32 = (const float*)(wtb + BIAS_O);
  const unsigned short* xn  = wtb + XN_O;
  const unsigned short* x2n = wtb + X2N_O;

  __shared__ unsigned bw[64 * 68];         // 17.4 KB: B half-tile (64 o rows)
  __shared__ unsigned short val[64][136];  // 17.4 KB: A tile (f16), pad 136
  __shared__ unsigned sidxw[KK * 4 * 64];  // 9.2 KB: [(tap*4+cr)*64+px] idx|w<<16
  float* om = (float*)&val[0][0];          // alias: om[oc*68+pp], 8.7 KB

  int t = threadIdx.x;
  int w = t >> 6;
  int mw = w & 1, nw = w >> 1;             // phase-3 2x2 wave grid
  int l15 = t & 15, quad = (t >> 4) & 3;
  int rb = blockIdx.x;
  int bid = (rb & 7) * 72 + (rb >> 3);     // XCD swizzle
  int b = bid / 144;
  int pblk = (bid % 144) * 64;

  // gather-role pixels: px = 16w + G*4 + quad
  int phg[4], pwg[4];
#pragma unroll
  for (int G = 0; G < 4; ++G) {
    int p = pblk + w * 16 + G * 4 + quad;
    phg[G] = p / WW;
    pwg[G] = p - phg[G] * WW;
  }

  // ===== phase 1: offset/mask GEMM =====
  f32x4 oa0 = {0.f, 0.f, 0.f, 0.f};
  f32x4 oa1 = {0.f, 0.f, 0.f, 0.f};
  const unsigned short* x2nb = x2n + ((size_t)b * HWSZ) * 128;
  for (int tap = 0; tap < KK; ++tap) {
    int ky = tap / 3 - 1, kx = tap % 3 - 1;
    uint4 vG[4];
#pragma unroll
    for (int G = 0; G < 4; ++G) {
      int y = phg[G] + ky, xx = pwg[G] + kx;
      bool ok = ((unsigned)y < HH) && ((unsigned)xx < WW);
      int pos = ok ? (y * WW + xx) : 0;
      uint4 v = *(const uint4*)(x2nb + ((size_t)pos << 7) + l15 * 8);
      vG[G] = ok ? v : make_uint4(0u, 0u, 0u, 0u);
    }
#pragma unroll
    for (int j = 0; j < 2; ++j) {          // stage 32 oc rows x 64 dw
      int cc = t + 256 * j;
      int row = cc >> 4, c16 = cc & 15;
      *(uint4*)&bw[row * 68 + c16 * 4] =
          *(const uint4*)(wt2b + (size_t)row * KTOT + tap * 128 + c16 * 8);
    }
#pragma unroll
    for (int G = 0; G < 4; ++G)
      *(uint4*)&val[w * 16 + G * 4 + quad][l15 * 8] = vG[G];
    __syncthreads();
#pragma unroll
    for (int ks = 0; ks < 4; ++ks) {
      f16x8 af = *(const f16x8*)&val[w * 16 + l15][ks * 32 + quad * 8];
      f16x8 b0 = *(const f16x8*)&bw[(size_t)l15 * 68 + ks * 16 + quad * 4];
      f16x8 b1 = *(const f16x8*)&bw[(size_t)(l15 + 16) * 68 + ks * 16 + quad * 4];
      oa0 = __builtin_amdgcn_mfma_f32_16x16x32_f16(af, b0, oa0, 0, 0, 0);
      oa1 = __builtin_amdgcn_mfma_f32_16x16x32_f16(af, b1, oa1, 0, 0, 0);
    }
    __syncthreads();
  }
  // dump om (+bias) into val-alias: col=px-in-block, row=oc.
  // val's A-tile is dead here (post final barrier of the tap loop).
#pragma unroll
  for (int nt = 0; nt < 2; ++nt) {
    f32x4 a = nt ? oa1 : oa0;
    int oc = nt * 16 + l15;
    float bia = bias32[oc];
#pragma unroll
    for (int r = 0; r < 4; ++r)
      om[oc * 68 + w * 16 + quad * 4 + r] = a[r] + bia;
  }
  __syncthreads();

  // ===== phase 2: bilinear params -> sidxw =====
  for (int e = t; e < KK * 64; e += 256) {
    int tap = e >> 6, pp = e & 63;
    int gp2 = pblk + pp;
    int h = gp2 / WW, ww_ = gp2 % WW;
    float dy = om[2 * tap * 68 + pp], dx = om[(2 * tap + 1) * 68 + pp];
    float mr = om[(18 + tap) * 68 + pp];
    float m = 1.f / (1.f + __expf(-mr));
    float py  = (float)(h + tap / 3 - 1) + dy;
    float pxx = (float)(ww_ + tap % 3 - 1) + dx;
    float y0f = floorf(py), x0f = floorf(pxx);
    int y0 = (int)y0f, x0 = (int)x0f;
    float ly = py - y0f, lx = pxx - x0f;
    int y1 = y0 + 1, x1 = x0 + 1;
    bool vy0 = (unsigned)y0 < HH, vy1 = (unsigned)y1 < HH;
    bool vx0 = (unsigned)x0 < WW, vx1 = (unsigned)x1 < WW;
    int cy0 = min(max(y0, 0), HH - 1), cy1 = min(max(y1, 0), HH - 1);
    int cx0 = min(max(x0, 0), WW - 1), cx1 = min(max(x1, 0), WW - 1);
    unsigned i00 = cy0 * WW + cx0, i01 = cy0 * WW + cx1;
    unsigned i10 = cy1 * WW + cx0, i11 = cy1 * WW + cx1;
    float w00 = (vy0 && vx0) ? m * (1.f - ly) * (1.f - lx) : 0.f;
    float w01 = (vy0 && vx1) ? m * (1.f - ly) * lx         : 0.f;
    float w10 = (vy1 && vx0) ? m * ly * (1.f - lx)         : 0.f;
    float w11 = (vy1 && vx1) ? m * ly * lx                 : 0.f;
    sidxw[(tap * 4 + 0) * 64 + pp] = i00 | ((unsigned)f2h(w00) << 16);
    sidxw[(tap * 4 + 1) * 64 + pp] = i01 | ((unsigned)f2h(w01) << 16);
    sidxw[(tap * 4 + 2) * 64 + pp] = i10 | ((unsigned)f2h(w10) << 16);
    sidxw[(tap * 4 + 3) * 64 + pp] = i11 | ((unsigned)f2h(w11) << 16);
  }
  __syncthreads();                          // om dead after this point

  // ===== phase 3: deformable GEMM (2x2 wave grid) =====
  // acc[h*4 + m*2 + ntl]: oc = h*64 + nw*32 + ntl*16 + l15,
  //                       px = mw*32 + m*16 + quad*4 + reg
  f32x4 acc[8];
#pragma unroll
  for (int nt = 0; nt < 8; ++nt) acc[nt] = (f32x4){0.f, 0.f, 0.f, 0.f};
  const unsigned short* xnb = xn + ((size_t)b * HWSZ) * 128;

  for (int tap = 0; tap < KK; ++tap) {
    // per-corner idx|weight for this lane's 4 gather pixels
    unsigned sw[4][4];
#pragma unroll
    for (int cr = 0; cr < 4; ++cr)
#pragma unroll
      for (int G = 0; G < 4; ++G)
        sw[cr][G] = sidxw[(tap * 4 + cr) * 64 + w * 16 + G * 4 + quad];
    // gather: one instr = full 256B rows of 4 pixels' corner cr
    uint4 v[4][4];
#pragma unroll
    for (int G = 0; G < 4; ++G)
#pragma unroll
      for (int cr = 0; cr < 4; ++cr)
        v[cr][G] = *(const uint4*)(xnb + ((size_t)(sw[cr][G] & 0xffffu) << 7) + l15 * 8);
    // combine corners in-lane (packed f16 FMA), write A tile
#pragma unroll
    for (int G = 0; G < 4; ++G) {
      h2 f[4];
#pragma unroll
      for (int j = 0; j < 4; ++j) f[j] = (h2){(_Float16)0.f, (_Float16)0.f};
#pragma unroll
      for (int cr = 0; cr < 4; ++cr) {
        _Float16 wh =
            __builtin_bit_cast(_Float16, (unsigned short)(sw[cr][G] >> 16));
        h2 wpk = {wh, wh};
        const h2* a = (const h2*)&v[cr][G];
#pragma unroll
        for (int j = 0; j < 4; ++j)
          f[j] += wpk * a[j];                    // v_pk_fma_f16
      }
      *(uint4*)&val[w * 16 + G * 4 + quad][l15 * 8] =
          make_uint4(__builtin_bit_cast(unsigned, f[0]),
                     __builtin_bit_cast(unsigned, f[1]),
                     __builtin_bit_cast(unsigned, f[2]),
                     __builtin_bit_cast(unsigned, f[3]));
    }
    // stage B half 0 (o rows 0..63)
#pragma unroll
    for (int j = 0; j < 4; ++j) {
      int cc = t + 256 * j;
      int row = cc >> 4, c16 = cc & 15;
      *(uint4*)&bw[row * 68 + c16 * 4] =
          *(const uint4*)(wtb + (size_t)row * KTOT + tap * 128 + c16 * 8);
    }
    __syncthreads();
    // af frags for BOTH m-tiles of this wave's 32-px band; reused both halves
    f16x8 af[2][4];
#pragma unroll
    for (int m = 0; m < 2; ++m)
#pragma unroll
      for (int ks = 0; ks < 4; ++ks)
        af[m][ks] =
            *(const f16x8*)&val[mw * 32 + m * 16 + l15][ks * 32 + quad * 8];
#pragma unroll
    for (int m = 0; m < 2; ++m)
#pragma unroll
      for (int ntl = 0; ntl < 2; ++ntl)
#pragma unroll
        for (int ks = 0; ks < 4; ++ks) {
          f16x8 bb = *(const f16x8*)&bw[(size_t)(nw * 32 + ntl * 16 + l15) * 68 +
                                        ks * 16 + quad * 4];
          acc[m * 2 + ntl] =
              __builtin_amdgcn_mfma_f32_16x16x32_f16(af[m][ks], bb,
                                                     acc[m * 2 + ntl], 0, 0, 0);
        }
    __syncthreads();
    // stage B half 1 (o rows 64..127)
#pragma unroll
    for (int j = 0; j < 4; ++j) {
      int cc = t + 256 * j;
      int row = cc >> 4, c16 = cc & 15;
      *(uint4*)&bw[row * 68 + c16 * 4] =
          *(const uint4*)(wtb + (size_t)(64 + row) * KTOT + tap * 128 + c16 * 8);
    }
    __syncthreads();
#pragma unroll
    for (int m = 0; m < 2; ++m)
#pragma unroll
      for (int ntl = 0; ntl < 2; ++ntl)
#pragma unroll
        for (int ks = 0; ks < 4; ++ks) {
          f16x8 bb = *(const f16x8*)&bw[(size_t)(nw * 32 + ntl * 16 + l15) * 68 +
                                        ks * 16 + quad * 4];
          acc[4 + m * 2 + ntl] =
              __builtin_amdgcn_mfma_f32_16x16x32_f16(af[m][ks], bb,
                                                     acc[4 + m * 2 + ntl], 0, 0, 0);
        }
    __syncthreads();
  }

  // ===== phase 4: direct epilogue (reg = 4 consecutive px -> float4 store) ===
#pragma unroll
  for (int h = 0; h < 2; ++h)
#pragma unroll
    for (int m = 0; m < 2; ++m)
#pragma unroll
      for (int ntl = 0; ntl < 2; ++ntl) {
        int oc = h * 64 + nw * 32 + ntl * 16 + l15;
        f32x4 a = acc[h * 4 + m * 2 + ntl];
        float db = defb[oc];
        float4 vv = make_float4(a[0] + db, a[1] + db, a[2] + db, a[3] + db);
        *(float4*)&out[((size_t)b * OUTC + oc) * HWSZ + pblk + mw * 32 +
                       m * 16 + quad * 4] = vv;
      }
}

extern "C" void kernel_launch(void* const* d_in, const int* in_sizes, int n_in,
                              void* d_out, int out_size, void* d_ws, size_t ws_size,
                              hipStream_t stream) {
  const float* x     = (const float*)d_in[0];
  const float* x2    = (const float*)d_in[1];
  const float* offw  = (const float*)d_in[2];
  const float* offb  = (const float*)d_in[3];
  const float* maskw = (const float*)d_in[4];
  const float* maskb = (const float*)d_in[5];
  const float* defw  = (const float*)d_in[6];
  const float* defb  = (const float*)d_in[7];
  float* out = (float*)d_out;

  hipLaunchKernelGGL(prep_all, dim3(1873), dim3(256), 0, stream,
                     x, x2, offw, maskw, defw, offb, maskb, d_ws);
  hipLaunchKernelGGL(fused, dim3(576), dim3(256), 0, stream, defb, d_ws, out);
}